// Round 2
// baseline (617.485 us; speedup 1.0000x reference)
//
#include <hip/hip_runtime.h>

// ADI diffusion: 2048 images of 128x128 fp32, 10 steps of (x half, y full,
// x half) tridiagonal solves. Factorizations precomputed per substep into
// g_FG by factor_kernel.
//
// R2: register-resident image. R1 fixed the scratch spill (3180->340 us) but
// left 1 wave/SIMD (66 KiB LDS image -> 2 blocks/CU, Occupancy 11.5%), so the
// serial Thomas chains (~30K dependent-fma cycles/wave) and the LDS session
// traffic (~160 us/CU of LDS pipe) serialize. Now the image lives in r[128]
// per thread across the whole kernel; LDS is only a 128x65 (33 KiB) buffer
// used to flip row<->column ownership (20 transposes). 33 KiB -> 4 blocks/CU
// -> 2 waves/SIMD: chains interleave, LDS overlaps compute, and the x-solve
// LDS round-trips disappear.
//
// Spill discipline (R1 lesson): r/tmp are never address-taken, all indices
// compile-time constant, vector ops only on LDS/global pointers.

#define EPSF 1e-6f
#define TSTR 65   // transpose buffer row stride (floats); all patterns <=2-way

__device__ float g_FG[30 * 256];   // per substep: F[128] then G[128]

// One block per substep s (0..29). coeff = smooth3(clip(base+lin*t+quad*t^2, EPS))*dt,
// then Thomas factorization: F_i = 1/dn_i, G_i = coeff_i/dn_i (cs_i = -G_i).
__global__ void factor_kernel(const float* __restrict__ abx,
                              const float* __restrict__ atx,
                              const float* __restrict__ aqx,
                              const float* __restrict__ bby,
                              const float* __restrict__ bty,
                              const float* __restrict__ bqy) {
  const int s = blockIdx.x;        // 0..29
  const int i = threadIdx.x;       // 0..127
  const int step = s / 3, phase = s - 3 * step;
  const float t  = 0.005f * (float)(2 * step + phase);
  const float dt = (phase == 1) ? 0.01f : 0.005f;
  const float* vb = (phase == 1) ? bby : abx;
  const float* vl = (phase == 1) ? bty : atx;
  const float* vq = (phase == 1) ? bqy : aqx;

  __shared__ float vv[128];
  __shared__ float cf[128];

  float v = vb[i] + vl[i] * t + vq[i] * t * t;
  v = fmaxf(v, EPSF);
  vv[i] = v;
  __syncthreads();
  float lft = vv[(i == 0)   ? 0   : (i - 1)];
  float rgt = vv[(i == 127) ? 127 : (i + 1)];
  cf[i] = (lft + v + rgt) * (1.0f / 3.0f) * dt;
  __syncthreads();

  if (i == 0) {
    float* Fo = g_FG + s * 256;
    float* Go = Fo + 128;
    float c0 = cf[0];
    float denom = 1.0f + c0 + EPSF;   // b[0] = 1 + coeff[0], + EPS
    float f = 1.0f / denom;
    float g = c0 * f;
    Fo[0] = f; Go[0] = g;
    float cs = -g;                    // cs_0 = c0/denom0
    for (int k = 1; k < 128; k++) {
      float ck = cf[k];
      float b  = (k == 127) ? (1.0f + ck) : (1.0f + 2.0f * ck);
      float dn = b + ck * cs + EPSF;  // b - a*cs + EPS, a = -coeff
      float fk = 1.0f / dn;
      float gk = ck * fk;
      Fo[k] = fk; Go[k] = gk;
      cs = -gk;
    }
  }
}

// Thomas substitution on a line held in registers.
// fwd: ds_i = d_i*F_i + G_i*ds_{i-1};  bwd: x_i = ds_i + G_i*x_{i+1}
__device__ __forceinline__ void solve_line(float (&r)[128],
                                           const float* __restrict__ Fs,
                                           const float* __restrict__ Gs) {
  r[0] *= Fs[0];
  #pragma unroll
  for (int i = 1; i < 128; i++) r[i] = fmaf(Gs[i], r[i - 1], r[i] * Fs[i]);
  #pragma unroll
  for (int i = 126; i >= 0; i--) r[i] = fmaf(Gs[i], r[i + 1], r[i]);
}

// Ownership flip (rows<->cols) through a half-image LDS buffer.
// Chunk c covers destination threads [64c, 64c+64): buf[h][j] = u[h][64c+j].
// Writes: contiguous b128, all threads (banks 2-way = free).
// Reads: stride-65 column b32, one wave (banks 2-way = free).
// Wave 0 must stash its old r[64..127] (needed for the chunk-1 write) in
// registers while absorbing its new state in chunk 0.
__device__ __forceinline__ void transpose_lds(float (&r)[128],
                                              float* __restrict__ buf,
                                              int tid) {
  const int lane = tid & 63;
  __syncthreads();                       // buf free (prior consumers done)
  // chunk 0 write: u[t][0..63]
  #pragma unroll
  for (int q = 0; q < 16; q++) {
    float4 t;
    t.x = r[4*q+0]; t.y = r[4*q+1]; t.z = r[4*q+2]; t.w = r[4*q+3];
    *(float4*)&buf[tid * TSTR + 4*q] = t;
  }
  __syncthreads();
  float tmp[64];
  if (tid < 64) {                        // wave 0: stash old tail, read new state
    #pragma unroll
    for (int j = 0; j < 64; j++) tmp[j] = r[64 + j];
    #pragma unroll
    for (int h = 0; h < 128; h++) r[h] = buf[h * TSTR + lane];
  }
  __syncthreads();
  // chunk 1 write: u[t][64..127] (wave 0 from stash, wave 1 from live r)
  if (tid < 64) {
    #pragma unroll
    for (int q = 0; q < 16; q++) {
      float4 t;
      t.x = tmp[4*q+0]; t.y = tmp[4*q+1]; t.z = tmp[4*q+2]; t.w = tmp[4*q+3];
      *(float4*)&buf[tid * TSTR + 4*q] = t;
    }
  } else {
    #pragma unroll
    for (int q = 0; q < 16; q++) {
      float4 t;
      t.x = r[64+4*q+0]; t.y = r[64+4*q+1]; t.z = r[64+4*q+2]; t.w = r[64+4*q+3];
      *(float4*)&buf[tid * TSTR + 4*q] = t;
    }
  }
  __syncthreads();
  if (tid >= 64) {                       // wave 1: read new state
    #pragma unroll
    for (int h = 0; h < 128; h++) r[h] = buf[h * TSTR + lane];
  }
  // next transpose's leading barrier protects buf from early rewrite
}

__global__ __launch_bounds__(128, 2) void diffusion_kernel(
    const float* __restrict__ uin,
    float* __restrict__ uout) {
  __shared__ float buf[128 * TSTR];      // 33280 B -> 4 blocks/CU
  const int tid = threadIdx.x;
  const long long ibase = (long long)blockIdx.x << 14;   // 16384 elems per image

  float r[128];

  // ---- load row tid (per-thread contiguous float4; 64B-line reuse across q
  //      keeps HBM fetch at 1x through L1/L2) ----
  {
    const float* gin = uin + ibase + tid * 128;
    #pragma unroll
    for (int q = 0; q < 32; q++) {
      float4 t = *(const float4*)(gin + 4*q);
      r[4*q+0] = t.x; r[4*q+1] = t.y; r[4*q+2] = t.z; r[4*q+3] = t.w;
    }
  }

  // substep sequence: x(s=0); per step k: y(s=3k+1); x(s=3k+2) merged with
  // x(s=3k+3) for k<9 (identical t -> identical factors).
  solve_line(r, g_FG, g_FG + 128);       // x, s=0 (row ownership)
  transpose_lds(r, buf, tid);            // rows -> cols

  #pragma unroll 1
  for (int k = 0; k < 10; k++) {
    const float* FGy = g_FG + (3 * k + 1) * 256;
    solve_line(r, FGy, FGy + 128);       // y (col ownership)
    transpose_lds(r, buf, tid);          // cols -> rows
    const float* FGx = g_FG + (3 * k + 2) * 256;
    solve_line(r, FGx, FGx + 128);       // x, s=3k+2
    if (k < 9) {
      solve_line(r, FGx, FGx + 128);     // merged x, s=3k+3 (same factors)
      transpose_lds(r, buf, tid);        // rows -> cols for next y
    }
  }

  // ---- store row tid ----
  {
    float* gout = uout + ibase + tid * 128;
    #pragma unroll
    for (int q = 0; q < 32; q++) {
      float4 t;
      t.x = r[4*q+0]; t.y = r[4*q+1]; t.z = r[4*q+2]; t.w = r[4*q+3];
      *(float4*)(gout + 4*q) = t;
    }
  }
}

extern "C" void kernel_launch(void* const* d_in, const int* in_sizes, int n_in,
                              void* d_out, int out_size, void* d_ws, size_t ws_size,
                              hipStream_t stream) {
  const float* u   = (const float*)d_in[0];
  const float* abx = (const float*)d_in[1];
  const float* bby = (const float*)d_in[4];
  const float* atx = (const float*)d_in[5];
  const float* bty = (const float*)d_in[8];
  const float* aqx = (const float*)d_in[9];
  const float* bqy = (const float*)d_in[12];
  float* out = (float*)d_out;

  factor_kernel<<<30, 128, 0, stream>>>(abx, atx, aqx, bby, bty, bqy);
  diffusion_kernel<<<2048, 128, 0, stream>>>(u, out);
}